// Round 13
// baseline (241.628 us; speedup 1.0000x reference)
//
#include <hip/hip_runtime.h>
#include <math.h>

// ---------------- problem constants ----------------
static constexpr int TOK    = 2048;
static constexpr int DIM_   = 1024;
static constexpr int NE     = 8;
static constexpr int INTER_ = 1408;
static constexpr int SINT   = 2816;
static constexpr int NSLOT  = TOK * 2;
static constexpr int KC     = 704;    // g2 K-chunk (22 steps of 32)

// ---------------- ws layout (bytes) ----------------
static constexpr size_t XB_OFF   = 0;                                    // [2048][1024] bf16
static constexpr size_t HR_OFF   = XB_OFF   + (size_t)TOK * DIM_ * 2;    // [4096][1408] bf16
static constexpr size_t HS_OFF   = HR_OFF   + (size_t)NSLOT * INTER_ * 2;// [2048][2816] bf16
static constexpr size_t W1B_OFF  = HS_OFF   + (size_t)TOK * SINT * 2;
static constexpr size_t W3B_OFF  = W1B_OFF  + (size_t)NE * INTER_ * DIM_ * 2;
static constexpr size_t W2B_OFF  = W3B_OFF  + (size_t)NE * INTER_ * DIM_ * 2;
static constexpr size_t SW1B_OFF = W2B_OFF  + (size_t)NE * DIM_ * INTER_ * 2;
static constexpr size_t SW3B_OFF = SW1B_OFF + (size_t)SINT * DIM_ * 2;
static constexpr size_t SW2B_OFF = SW3B_OFF + (size_t)SINT * DIM_ * 2;
static constexpr size_t TOPK_OFF = SW2B_OFF + (size_t)DIM_ * SINT * 2;
static constexpr size_t SCALE_OFF= TOPK_OFF + (size_t)TOK * 2 * 4;
static constexpr size_t SLOT_OFF = SCALE_OFF+ (size_t)TOK * 4;
static constexpr size_t ROWT_OFF = SLOT_OFF + (size_t)TOK * 2 * 4;
static constexpr size_t WL_OFF   = ROWT_OFF + (size_t)NSLOT * 4 + 1024;  // wl13 int4[48]
static constexpr size_t WL2_OFF  = WL_OFF   + 48 * 16;                   // wl2 int4[80]

// ---------------- types / helpers ----------------
typedef unsigned short u16;
typedef u16   u16x4  __attribute__((ext_vector_type(4)));
typedef u16   u16x8  __attribute__((ext_vector_type(8)));
typedef __bf16 bf16x8 __attribute__((ext_vector_type(8)));
typedef float f32x4  __attribute__((ext_vector_type(4)));

static __device__ __forceinline__ u16 f2bf(float f) {
  unsigned int u = __builtin_bit_cast(unsigned int, f);
  return (u16)((u + 0x7fffu + ((u >> 16) & 1u)) >> 16);   // RNE
}
static __device__ __forceinline__ float bf2f(u16 h) {
  unsigned int u = ((unsigned int)h) << 16;
  return __builtin_bit_cast(float, u);
}
static __device__ __forceinline__ f32x4 mfma16(u16x8 a, u16x8 b, f32x4 c) {
  return __builtin_amdgcn_mfma_f32_16x16x32_bf16(
      __builtin_bit_cast(bf16x8, a), __builtin_bit_cast(bf16x8, b), c, 0, 0, 0);
}
static __device__ __forceinline__ void gload16(const void* g, void* l) {
  __builtin_amdgcn_global_load_lds(
      (const __attribute__((address_space(1))) unsigned int*)g,
      (__attribute__((address_space(3))) unsigned int*)l, 16, 0, 0);
}
// counted vmcnt: keep newer prefetch loads in flight across the barrier (T4)
#define WAITV(N) asm volatile("s_waitcnt vmcnt(" #N ")" ::: "memory")

// =====================================================================
// gate + conversion of x, w1, w3, sw1, sw3 (g13 inputs), row-major bf16.
// blocks [0,512): x->bf16 + gate + zero y_out.  [512,512+7040): weights.
// =====================================================================
__global__ __launch_bounds__(256) void gate_conv_kernel(
    const float* __restrict__ x, const float* __restrict__ gw,
    const float* __restrict__ gb,
    const float* __restrict__ w1, const float* __restrict__ w3,
    const float* __restrict__ sw1, const float* __restrict__ sw3,
    u16* __restrict__ xb, u16* __restrict__ w1b, u16* __restrict__ w3b,
    u16* __restrict__ sw1b, u16* __restrict__ sw3b,
    float* __restrict__ probs_out, float* __restrict__ idx_out,
    int* __restrict__ topk, float* __restrict__ scalep,
    float* __restrict__ y_out)
{
  const int tid = threadIdx.x;
  if (blockIdx.x >= 512) {
    int g = blockIdx.x - 512;
    const float* src; u16* dst;
    if      (g < 2816) {            src = w1;  dst = w1b;  }
    else if (g < 5632) { g -= 2816; src = w3;  dst = w3b;  }
    else if (g < 6336) { g -= 5632; src = sw1; dst = sw1b; }
    else               { g -= 6336; src = sw3; dst = sw3b; }
    const size_t base = (size_t)g * 4096 + (size_t)tid * 16;
    #pragma unroll
    for (int j = 0; j < 4; ++j) {
      float4 v = *(const float4*)(src + base + j * 4);
      *(u16x4*)(dst + base + j * 4) =
          (u16x4){ f2bf(v.x), f2bf(v.y), f2bf(v.z), f2bf(v.w) };
    }
    return;
  }
  // ---- zero y_out slice (g2 accumulates atomically into it) ----
  {
    float4 z4 = {0.f, 0.f, 0.f, 0.f};
    float* yz = y_out + (size_t)blockIdx.x * 4096 + (size_t)tid * 16;
    #pragma unroll
    for (int j = 0; j < 4; ++j) *(float4*)(yz + j * 4) = z4;
  }
  // ---- x -> bf16 ----
  {
    const size_t base = (size_t)blockIdx.x * 4096 + (size_t)tid * 16;
    const float4* src = (const float4*)(x + base);
    u16* dst = xb + base;
    #pragma unroll
    for (int j = 0; j < 4; ++j) {
      float4 v = src[j];
      *(u16x4*)(dst + j * 4) = (u16x4){ f2bf(v.x), f2bf(v.y), f2bf(v.z), f2bf(v.w) };
    }
  }
  // ---- gate: one wave per token (f64 for exact top-2 vs np ref) ----
  const int wid = tid >> 6, lane = tid & 63;
  const int t = blockIdx.x * 4 + wid;
  const float* xr = x + (size_t)t * DIM_;
  double part[NE] = {0,0,0,0,0,0,0,0};
  for (int it = 0; it < DIM_ / 64; ++it) {
    const int d = lane + it * 64;
    const double xv = (double)xr[d];
    #pragma unroll
    for (int e = 0; e < NE; ++e) part[e] += xv * (double)gw[e * DIM_ + d];
  }
  #pragma unroll
  for (int e = 0; e < NE; ++e) {
    #pragma unroll
    for (int off = 32; off; off >>= 1) part[e] += __shfl_xor(part[e], off);
    part[e] += (double)gb[e];
  }
  if (lane == 0) {
    double m = part[0];
    #pragma unroll
    for (int e = 1; e < NE; ++e) m = fmax(m, part[e]);
    double p[NE], sd = 0.0;
    #pragma unroll
    for (int e = 0; e < NE; ++e) { p[e] = exp(part[e] - m); sd += p[e]; }
    float pf[NE]; float sumf = 0.0f;
    #pragma unroll
    for (int e = 0; e < NE; ++e) { pf[e] = (float)(p[e] / sd); sumf += pf[e]; }
    int a0 = 0;
    #pragma unroll
    for (int e = 1; e < NE; ++e) if (part[e] > part[a0]) a0 = e;
    int a1 = (a0 == 0) ? 1 : 0;
    #pragma unroll
    for (int e = 0; e < NE; ++e) if (e != a0 && part[e] > part[a1]) a1 = e;
    #pragma unroll
    for (int e = 0; e < NE; ++e) probs_out[t * NE + e] = pf[e];
    idx_out[t * 2 + 0] = (float)a0;
    idx_out[t * 2 + 1] = (float)a1;
    topk[t * 2 + 0] = a0; topk[t * 2 + 1] = a1;
    scalep[t] = sumf;
  }
}

// =====================================================================
// plan: histogram + bases + deterministic stable scatter + worklists.
// One block, 256 threads.
// wl13: {z, rowbase, rows, 0}  (<=40 entries, pad -1)
// wl2 : routed {e, rowbase, rows, kh<2} + shared {NE, rowbase, 256, q<4}
// =====================================================================
__global__ __launch_bounds__(256) void plan_kernel(
    const int* __restrict__ topk, int4* __restrict__ wl13,
    int4* __restrict__ wl2,
    int* __restrict__ row_token, int* __restrict__ slot_of)
{
  __shared__ int pc[256][NE];     // per-thread per-expert counts (8 KB)
  __shared__ int base[NE], tot[NE];
  const int tid = threadIdx.x;
  int loc[NE] = {0,0,0,0,0,0,0,0};
  #pragma unroll 1
  for (int i = 0; i < 16; ++i) ++loc[topk[tid * 16 + i]];
  #pragma unroll
  for (int e = 0; e < NE; ++e) pc[tid][e] = loc[e];
  __syncthreads();
  if (tid < NE) {                  // exclusive scan over threads, expert tid
    int acc = 0;
    for (int th = 0; th < 256; ++th) { int v = pc[th][tid]; pc[th][tid] = acc; acc += v; }
    tot[tid] = acc;
  }
  __syncthreads();
  if (tid == 0) {
    int acc = 0;
    for (int e = 0; e < NE; ++e) { base[e] = acc; acc += tot[e]; }
    int n = 0;
    for (int e = 0; e < NE; ++e)
      for (int r = 0; r < tot[e]; r += 256)
        wl13[n++] = make_int4(e, base[e] + r, min(256, tot[e] - r), 0);
    for (int h = 0; h < 2; ++h)
      for (int mt = 0; mt < 8; ++mt)
        wl13[n++] = make_int4(NE + h, mt * 256, 256, 0);
    for (int i = n; i < 48; ++i) wl13[i] = make_int4(-1, 0, 0, 0);
    int n2 = 0;
    for (int e = 0; e < NE; ++e)
      for (int r = 0; r < tot[e]; r += 256)
        for (int kh = 0; kh < 2; ++kh)
          wl2[n2++] = make_int4(e, base[e] + r, min(256, tot[e] - r), kh);
    for (int q = 0; q < 4; ++q)
      for (int mt = 0; mt < 8; ++mt)
        wl2[n2++] = make_int4(NE, mt * 256, 256, q);
    for (int i = n2; i < 80; ++i) wl2[i] = make_int4(-1, 0, 0, 0);
  }
  __syncthreads();
  int pos[NE];
  #pragma unroll
  for (int e = 0; e < NE; ++e) pos[e] = base[e] + pc[tid][e];
  #pragma unroll 1
  for (int i = 0; i < 16; ++i) {
    const int gi = tid * 16 + i;          // gi = token*2 + k
    const int e = topk[gi];
    const int s = pos[e]++;
    row_token[s] = gi >> 1;
    slot_of[gi] = s;
  }
}

// =====================================================================
// g13 (r12, unchanged): H = silu(A@W1^T+b1)*(A@W3^T+b3).
// 512 thr / 8 waves, BM=256, BN=64 (dual B), BK=32, LDS 48KB.
// 2-barrier double-buffer, counted vmcnt(3), XOR swizzle, setprio.
// blockIdx.y in [0,40): GEMM tile wl13[y]; [40,48): w2/sw2 conversion.
// =====================================================================
__global__ __launch_bounds__(512) void g13_kernel(
    const u16* __restrict__ xb, const int* __restrict__ row_token,
    const int4* __restrict__ wl,
    const u16* __restrict__ w1b, const float* __restrict__ b1,
    const u16* __restrict__ w3b, const float* __restrict__ b3,
    const u16* __restrict__ sw1b, const float* __restrict__ sb1,
    const u16* __restrict__ sw3b, const float* __restrict__ sb3,
    u16* __restrict__ Hr, u16* __restrict__ Hs,
    const float* __restrict__ w2f, const float* __restrict__ sw2f,
    u16* __restrict__ w2b, u16* __restrict__ sw2b)
{
  constexpr int K = DIM_;          // 1024
  constexpr int NT = K / 32;       // 32
  const int tid = threadIdx.x, wid = tid >> 6, lane = tid & 63;

  if (blockIdx.y >= 40) {          // ---- overlapped w2/sw2 conversion ----
    const int cid = (blockIdx.y - 40) * 22 + blockIdx.x;   // [0,176)
    for (int chunk = cid; chunk < 1760; chunk += 176) {
      int g = chunk; const float* src; u16* dst;
      if (g < 1408) { src = w2f;  dst = w2b;  }
      else { g -= 1408; src = sw2f; dst = sw2b; }
      const size_t base = (size_t)g * 8192 + (size_t)tid * 16;
      #pragma unroll
      for (int j = 0; j < 4; ++j) {
        float4 v = *(const float4*)(src + base + j * 4);
        *(u16x4*)(dst + base + j * 4) =
            (u16x4){ f2bf(v.x), f2bf(v.y), f2bf(v.z), f2bf(v.w) };
      }
    }
    return;
  }

  const int4 it = wl[blockIdx.y];
  const int z = it.x;
  if (z < 0) return;
  const int rowbase = it.y, rows_lim = it.z;
  const int col0 = blockIdx.x * 64;

  const int lrow = lane >> 2;
  const int sce = ((lane & 3) ^ ((lane >> 3) & 3)) * 8;   // swizzled src col

  const u16 *W1, *W3; const float *B1p, *B3p;
  u16* Hbase; int ldh;
  const u16* aptr[2];

  if (z < NE) {
    #pragma unroll
    for (int q = 0; q < 2; ++q) {
      const int rq = wid * 32 + q * 16 + lrow;
      const int t = (rq < rows_lim) ? row_token[rowbase + rq] : 0;
      aptr[q] = xb + (size_t)t * K + sce;
    }
    W1 = w1b + (size_t)z * INTER_ * K;  W3 = w3b + (size_t)z * INTER_ * K;
    B1p = b1 + z * INTER_;              B3p = b3 + z * INTER_;
    Hbase = Hr + (size_t)rowbase * INTER_;  ldh = INTER_;
  } else {
    const int h = z - NE;
    #pragma unroll
    for (int q = 0; q < 2; ++q) {
      const int rq = wid * 32 + q * 16 + lrow;
      aptr[q] = xb + (size_t)(rowbase + min(rq, rows_lim - 1)) * K + sce;
    }
    W1 = sw1b + (size_t)h * INTER_ * K;  W3 = sw3b + (size_t)h * INTER_ * K;
    B1p = sb1 + h * INTER_;              B3p = sb3 + h * INTER_;
    Hbase = Hs + (size_t)rowbase * SINT + h * INTER_;  ldh = SINT;
  }

  __shared__ alignas(16) u16 Al [2][256 * 32];   // 32 KB
  __shared__ alignas(16) u16 B1l[2][64 * 32];    //  8 KB
  __shared__ alignas(16) u16 B3l[2][64 * 32];    //  8 KB

  const int brole = wid >> 2, bw = wid & 3;
  const u16* bsrc = (brole ? W3 : W1) + (size_t)(col0 + bw * 16 + lrow) * K + sce;
  u16* bdst0 = brole ? &B3l[0][bw * 512] : &B1l[0][bw * 512];
  u16* bdst1 = brole ? &B3l[1][bw * 512] : &B1l[1][bw * 512];

  #define G13_STAGE(p, kt) {                                          \
    const int k0_ = (kt) * 32;                                        \
    gload16(aptr[0] + k0_, &Al[p][(wid * 2 + 0) * 512]);              \
    gload16(aptr[1] + k0_, &Al[p][(wid * 2 + 1) * 512]);              \
    gload16(bsrc + k0_, (p) ? bdst1 : bdst0);                         \
  }

  G13_STAGE(0, 0);

  const int wr = wid >> 1, wc = wid & 1, fr = lane & 15, gr = lane >> 4;
  const int key = (fr >> 1) & 3;
  f32x4 acc1[4][2] = {}, acc3[4][2] = {};
  int p = 0;

  #pragma unroll 1
  for (int kt = 0; kt < NT; ++kt) {
    if (kt + 1 < NT) { G13_STAGE(p ^ 1, kt + 1); WAITV(3); }
    else             { WAITV(0); }
    __builtin_amdgcn_s_barrier();
    u16x8 af[4], b1f[2], b3f[2];
    #pragma unroll
    for (int mi = 0; mi < 4; ++mi)
      af[mi] = *(const u16x8*)&Al[p][(wr * 64 + mi * 16 + fr) * 32 + ((gr ^ key) * 8)];
    #pragma unroll
    for (int ni = 0; ni < 2; ++ni) {
      const int off = (wc * 32 + ni * 16 + fr) * 32 + ((gr ^ key) * 8);
      b1f[ni] = *(const u16x8*)&B1l[p][off];
      b3f[ni] = *(const u16x8*)&B3l[p][off];
    }
    __builtin_amdgcn_s_setprio(1);
    #pragma unroll
    for (int mi = 0; mi < 4; ++mi)
      #pragma unroll
      for (int ni = 0; ni < 2; ++ni) {
        acc1[mi][ni] = mfma16(af[mi], b1f[ni], acc1[mi][ni]);
        acc3[mi][ni] = mfma16(af[mi], b3f[ni], acc3[mi][ni]);
      }
    __builtin_amdgcn_s_setprio(0);
    __builtin_amdgcn_s_barrier();
    p ^= 1;
  }
  #undef G13_STAGE

  #pragma unroll
  for (int ni = 0; ni < 2; ++ni) {
    const int gcol = col0 + wc * 32 + ni * 16 + fr;
    const float bb1 = B1p[gcol], bb3 = B3p[gcol];
    #pragma unroll
    for (int mi = 0; mi < 4; ++mi) {
      const int rb = wr * 64 + mi * 16 + gr * 4;
      #pragma unroll
      for (int j = 0; j < 4; ++j) {
        const int r = rb + j;
        if (r < rows_lim) {
          const float h1 = acc1[mi][ni][j] + bb1;
          const float h3 = acc3[mi][ni][j] + bb3;
          const float hv = (h1 / (1.0f + __expf(-h1))) * h3;
          Hbase[(size_t)r * ldh + gcol] = f2bf(hv);
        }
      }
    }
  }
}

// =====================================================================
// g2 + fused combine: split-K (KC=704), atomic-accumulate into y_out.
// 512 thr / 8 waves (4M x 2N), BM=256, BN=128, BK=32, 22 K-steps.
// Triple-buffered, depth-2 prefetch, one barrier/step, vmcnt(3).
// wl2: z<8 routed {e, slotbase, rows, kh}: y += (H_r@W2^T + b2?)*scale
//      z==8 shared {_, tokbase, 256, q}:  y += Hs_q@sw2_q^T + sb2?
// =====================================================================
__global__ __launch_bounds__(512) void g2_kernel(
    const u16* __restrict__ Hr, const u16* __restrict__ Hs,
    const int4* __restrict__ wl2, const int* __restrict__ row_token,
    const float* __restrict__ scalep,
    const u16* __restrict__ w2b, const float* __restrict__ b2,
    const u16* __restrict__ sw2b, const float* __restrict__ sb2,
    float* __restrict__ y_out)
{
  constexpr int NT = KC / 32;       // 22
  const int4 it = wl2[blockIdx.y];
  const int z = it.x;
  if (z < 0) return;
  const int rowbase = it.y, rows_lim = it.z, kq = it.w;
  const int col0 = blockIdx.x * 128;

  const int tid = threadIdx.x, wid = tid >> 6, lane = tid & 63;
  const int lrow = lane >> 2;
  const int sce = ((lane & 3) ^ ((lane >> 3) & 3)) * 8;

  const u16 *Abase, *W;
  int ldA, ldW;
  const bool routed = (z < NE);
  if (routed) {
    Abase = Hr + (size_t)rowbase * INTER_ + kq * KC;          ldA = INTER_;
    W = w2b + (size_t)z * DIM_ * INTER_ + kq * KC;            ldW = INTER_;
  } else {
    Abase = Hs + (size_t)rowbase * SINT + kq * KC;            ldA = SINT;
    W = sw2b + kq * KC;                                       ldW = SINT;
  }

  const u16* aptr[2];
  #pragma unroll
  for (int q = 0; q < 2; ++q) {
    const int rq = wid * 32 + q * 16 + lrow;
    aptr[q] = Abase + (size_t)min(rq, rows_lim - 1) * ldA + sce;
  }
  const u16* wsrc = W + (size_t)(col0 + wid * 16 + lrow) * ldW + sce;

  __shared__ alignas(16) u16 Al[3][256 * 32];   // 48 KB
  __shared__ alignas(16) u16 Bl[3][128 * 32];   // 24 KB

  #define G2_STAGE(p, kt) {                                           \
    const int k0_ = (kt) * 32;                                        \
    gload16(aptr[0] + k0_, &Al[p][(wid * 2 + 0) * 512]);              \
    gload16(aptr[1] + k0_, &Al[p][(wid * 2 + 1) * 512]);              \
    gload16(wsrc + k0_, &Bl[p][wid * 512]);                           \
  }

  G2_STAGE(0, 0);
  G2_STAGE(1, 1);   // 6 loads/wave in flight (2 stages)

  const int wr = wid >> 1, wc = wid & 1, fr = lane & 15, gr = lane >> 4;
  const int key = (fr >> 1) & 3;
  f32x4 acc[4][4] = {};
  int cur = 0;

  #pragma unroll 1
  for (int kt = 0; kt < NT; ++kt) {
    if (kt + 1 < NT) { WAITV(3); }   // stage kt done; stage kt+1 in flight
    else             { WAITV(0); }
    __builtin_amdgcn_s_barrier();    // all waves done reading buf[(kt+2)%3]
    if (kt + 2 < NT) {
      const int nx = (cur + 2 >= 3) ? cur - 1 : cur + 2;
      G2_STAGE(nx, kt + 2);
    }
    u16x8 af[4], bf_[4];
    #pragma unroll
    for (int mi = 0; mi < 4; ++mi)
      af[mi] = *(const u16x8*)&Al[cur][(wr * 64 + mi * 16 + fr) * 32 + ((gr ^ key) * 8)];
    #pragma unroll
    for (int ni = 0; ni < 4; ++ni)
      bf_[ni] = *(const u16x8*)&Bl[cur][(wc * 64 + ni * 16 + fr) * 32 + ((gr ^ key) * 8)];
    __builtin_amdgcn_s_setprio(1);
    #pragma unroll
    for (int mi = 0; mi < 4; ++mi)
      #pragma unroll
      for (int ni = 0; ni < 4; ++ni)
        acc[mi][ni] = mfma16(af[mi], bf_[ni], acc[mi][ni]);
    __builtin_amdgcn_s_setprio(0);
    cur = (cur + 1 == 3) ? 0 : cur + 1;
  }
  #undef G2_STAGE

  // ---- fused combine: atomic accumulate into y_out ----
  #pragma unroll
  for (int ni = 0; ni < 4; ++ni) {
    const int gcol = col0 + wc * 64 + ni * 16 + fr;
    float bb = 0.0f;
    if (kq == 0) bb = routed ? b2[z * DIM_ + gcol] : sb2[gcol];
    #pragma unroll
    for (int mi = 0; mi < 4; ++mi) {
      const int rb = wr * 64 + mi * 16 + gr * 4;
      #pragma unroll
      for (int j = 0; j < 4; ++j) {
        const int r = rb + j;
        if (r < rows_lim) {
          if (routed) {
            const int tok = row_token[rowbase + r];
            atomicAdd(&y_out[(size_t)tok * DIM_ + gcol],
                      (acc[mi][ni][j] + bb) * scalep[tok]);
          } else {
            atomicAdd(&y_out[(size_t)(rowbase + r) * DIM_ + gcol],
                      acc[mi][ni][j] + bb);
          }
        }
      }
    }
  }
}

// =====================================================================
extern "C" void kernel_launch(void* const* d_in, const int* in_sizes, int n_in,
                              void* d_out, int out_size, void* d_ws, size_t ws_size,
                              hipStream_t stream) {
  (void)in_sizes; (void)n_in; (void)out_size; (void)ws_size;
  const float* x   = (const float*)d_in[0];
  const float* gw  = (const float*)d_in[1];
  const float* gb  = (const float*)d_in[2];
  const float* w1  = (const float*)d_in[3];
  const float* b1  = (const float*)d_in[4];
  const float* w2  = (const float*)d_in[5];
  const float* b2  = (const float*)d_in[6];
  const float* w3  = (const float*)d_in[7];
  const float* b3  = (const float*)d_in[8];
  const float* sw1 = (const float*)d_in[9];
  const float* sb1 = (const float*)d_in[10];
  const float* sw2 = (const float*)d_in[11];
  const float* sb2 = (const float*)d_in[12];
  const float* sw3 = (const float*)d_in[13];
  const float* sb3 = (const float*)d_in[14];

  float* out       = (float*)d_out;
  float* probs_out = out;
  float* idx_out   = out + TOK * NE;
  float* y_out     = out + TOK * NE + TOK * 2;

  char* ws = (char*)d_ws;
  u16*   xb        = (u16*)  (ws + XB_OFF);
  u16*   Hr        = (u16*)  (ws + HR_OFF);
  u16*   Hs        = (u16*)  (ws + HS_OFF);
  u16*   w1b       = (u16*)  (ws + W1B_OFF);
  u16*   w3b       = (u16*)  (ws + W3B_OFF);
  u16*   w2b       = (u16*)  (ws + W2B_OFF);
  u16*   sw1b      = (u16*)  (ws + SW1B_OFF);
  u16*   sw3b      = (u16*)  (ws + SW3B_OFF);
  u16*   sw2b      = (u16*)  (ws + SW2B_OFF);
  int*   topk      = (int*)  (ws + TOPK_OFF);
  float* scalep    = (float*)(ws + SCALE_OFF);
  int*   slot_of   = (int*)  (ws + SLOT_OFF);
  int*   row_token = (int*)  (ws + ROWT_OFF);
  int4*  wl13      = (int4*) (ws + WL_OFF);
  int4*  wl2       = (int4*) (ws + WL2_OFF);

  gate_conv_kernel<<<512 + 7040, 256, 0, stream>>>(
      x, gw, gb, w1, w3, sw1, sw3,
      xb, w1b, w3b, sw1b, sw3b,
      probs_out, idx_out, topk, scalep, y_out);
  plan_kernel<<<1, 256, 0, stream>>>(topk, wl13, wl2, row_token, slot_of);
  g13_kernel<<<dim3(22, 48), 512, 0, stream>>>(
      xb, row_token, wl13, w1b, b1, w3b, b3, sw1b, sb1, sw3b, sb3, Hr, Hs,
      w2, sw2, w2b, sw2b);
  g2_kernel<<<dim3(8, 80), 512, 0, stream>>>(
      Hr, Hs, wl2, row_token, scalep, w2b, b2, sw2b, sb2, y_out);
}

// Round 14
// 214.066 us; speedup vs baseline: 1.1288x; 1.1288x over previous
//
#include <hip/hip_runtime.h>
#include <math.h>

// ---------------- problem constants ----------------
static constexpr int TOK    = 2048;
static constexpr int DIM_   = 1024;
static constexpr int NE     = 8;
static constexpr int INTER_ = 1408;
static constexpr int SINT   = 2816;
static constexpr int NSLOT  = TOK * 2;

// ---------------- ws layout (bytes) ----------------
static constexpr size_t XB_OFF   = 0;                                    // [2048][1024] bf16
static constexpr size_t HR_OFF   = XB_OFF   + (size_t)TOK * DIM_ * 2;    // [4096][1408] bf16
static constexpr size_t HS_OFF   = HR_OFF   + (size_t)NSLOT * INTER_ * 2;// [2048][2816] bf16
static constexpr size_t YS_OFF   = HS_OFF   + (size_t)TOK * SINT * 2;    // [4096][1024] bf16
static constexpr size_t ZP_OFF   = YS_OFF   + (size_t)NSLOT * DIM_ * 2;  // [2][2048][1024] f32
static constexpr size_t W1B_OFF  = ZP_OFF   + (size_t)2 * TOK * DIM_ * 4;
static constexpr size_t W3B_OFF  = W1B_OFF  + (size_t)NE * INTER_ * DIM_ * 2;
static constexpr size_t W2B_OFF  = W3B_OFF  + (size_t)NE * INTER_ * DIM_ * 2;
static constexpr size_t SW1B_OFF = W2B_OFF  + (size_t)NE * DIM_ * INTER_ * 2;
static constexpr size_t SW3B_OFF = SW1B_OFF + (size_t)SINT * DIM_ * 2;
static constexpr size_t SW2B_OFF = SW3B_OFF + (size_t)SINT * DIM_ * 2;
static constexpr size_t TOPK_OFF = SW2B_OFF + (size_t)DIM_ * SINT * 2;
static constexpr size_t SCALE_OFF= TOPK_OFF + (size_t)TOK * 2 * 4;
static constexpr size_t SLOT_OFF = SCALE_OFF+ (size_t)TOK * 4;
static constexpr size_t ROWT_OFF = SLOT_OFF + (size_t)TOK * 2 * 4;
static constexpr size_t WL_OFF   = ROWT_OFF + (size_t)NSLOT * 4 + 1024;  // int4[64]

// ---------------- types / helpers ----------------
typedef unsigned short u16;
typedef u16   u16x4  __attribute__((ext_vector_type(4)));
typedef u16   u16x8  __attribute__((ext_vector_type(8)));
typedef __bf16 bf16x8 __attribute__((ext_vector_type(8)));
typedef float f32x4  __attribute__((ext_vector_type(4)));

static __device__ __forceinline__ u16 f2bf(float f) {
  unsigned int u = __builtin_bit_cast(unsigned int, f);
  return (u16)((u + 0x7fffu + ((u >> 16) & 1u)) >> 16);   // RNE
}
static __device__ __forceinline__ float bf2f(u16 h) {
  unsigned int u = ((unsigned int)h) << 16;
  return __builtin_bit_cast(float, u);
}
static __device__ __forceinline__ f32x4 mfma16(u16x8 a, u16x8 b, f32x4 c) {
  return __builtin_amdgcn_mfma_f32_16x16x32_bf16(
      __builtin_bit_cast(bf16x8, a), __builtin_bit_cast(bf16x8, b), c, 0, 0, 0);
}
static __device__ __forceinline__ void gload16(const void* g, void* l) {
  __builtin_amdgcn_global_load_lds(
      (const __attribute__((address_space(1))) unsigned int*)g,
      (__attribute__((address_space(3))) unsigned int*)l, 16, 0, 0);
}
// counted vmcnt: keep newer prefetch loads in flight across the barrier (T4)
#define WAITV(N) asm volatile("s_waitcnt vmcnt(" #N ")" ::: "memory")

// =====================================================================
// gate + conversion of x, w1, w3, sw1, sw3 (g13 inputs), row-major bf16.
// blocks [0,512): x->bf16 + gate.  blocks [512, 512+7040): weights.
// =====================================================================
__global__ __launch_bounds__(256) void gate_conv_kernel(
    const float* __restrict__ x, const float* __restrict__ gw,
    const float* __restrict__ gb,
    const float* __restrict__ w1, const float* __restrict__ w3,
    const float* __restrict__ sw1, const float* __restrict__ sw3,
    u16* __restrict__ xb, u16* __restrict__ w1b, u16* __restrict__ w3b,
    u16* __restrict__ sw1b, u16* __restrict__ sw3b,
    float* __restrict__ probs_out, float* __restrict__ idx_out,
    int* __restrict__ topk, float* __restrict__ scalep)
{
  const int tid = threadIdx.x;
  if (blockIdx.x >= 512) {
    int g = blockIdx.x - 512;
    const float* src; u16* dst;
    if      (g < 2816) {            src = w1;  dst = w1b;  }
    else if (g < 5632) { g -= 2816; src = w3;  dst = w3b;  }
    else if (g < 6336) { g -= 5632; src = sw1; dst = sw1b; }
    else               { g -= 6336; src = sw3; dst = sw3b; }
    const size_t base = (size_t)g * 4096 + (size_t)tid * 16;
    #pragma unroll
    for (int j = 0; j < 4; ++j) {
      float4 v = *(const float4*)(src + base + j * 4);
      *(u16x4*)(dst + base + j * 4) =
          (u16x4){ f2bf(v.x), f2bf(v.y), f2bf(v.z), f2bf(v.w) };
    }
    return;
  }
  // ---- x -> bf16 ----
  {
    const size_t base = (size_t)blockIdx.x * 4096 + (size_t)tid * 16;
    const float4* src = (const float4*)(x + base);
    u16* dst = xb + base;
    #pragma unroll
    for (int j = 0; j < 4; ++j) {
      float4 v = src[j];
      *(u16x4*)(dst + j * 4) = (u16x4){ f2bf(v.x), f2bf(v.y), f2bf(v.z), f2bf(v.w) };
    }
  }
  // ---- gate: one wave per token (f64 for exact top-2 vs np ref) ----
  const int wid = tid >> 6, lane = tid & 63;
  const int t = blockIdx.x * 4 + wid;
  const float* xr = x + (size_t)t * DIM_;
  double part[NE] = {0,0,0,0,0,0,0,0};
  for (int it = 0; it < DIM_ / 64; ++it) {
    const int d = lane + it * 64;
    const double xv = (double)xr[d];
    #pragma unroll
    for (int e = 0; e < NE; ++e) part[e] += xv * (double)gw[e * DIM_ + d];
  }
  #pragma unroll
  for (int e = 0; e < NE; ++e) {
    #pragma unroll
    for (int off = 32; off; off >>= 1) part[e] += __shfl_xor(part[e], off);
    part[e] += (double)gb[e];
  }
  if (lane == 0) {
    double m = part[0];
    #pragma unroll
    for (int e = 1; e < NE; ++e) m = fmax(m, part[e]);
    double p[NE], sd = 0.0;
    #pragma unroll
    for (int e = 0; e < NE; ++e) { p[e] = exp(part[e] - m); sd += p[e]; }
    float pf[NE]; float sumf = 0.0f;
    #pragma unroll
    for (int e = 0; e < NE; ++e) { pf[e] = (float)(p[e] / sd); sumf += pf[e]; }
    int a0 = 0;
    #pragma unroll
    for (int e = 1; e < NE; ++e) if (part[e] > part[a0]) a0 = e;
    int a1 = (a0 == 0) ? 1 : 0;
    #pragma unroll
    for (int e = 0; e < NE; ++e) if (e != a0 && part[e] > part[a1]) a1 = e;
    #pragma unroll
    for (int e = 0; e < NE; ++e) probs_out[t * NE + e] = pf[e];
    idx_out[t * 2 + 0] = (float)a0;
    idx_out[t * 2 + 1] = (float)a1;
    topk[t * 2 + 0] = a0; topk[t * 2 + 1] = a1;
    scalep[t] = sumf;
  }
}

// =====================================================================
// plan: histogram + bases + deterministic stable scatter + worklist.
// One block, 256 threads.
// =====================================================================
__global__ __launch_bounds__(256) void plan_kernel(
    const int* __restrict__ topk, int4* __restrict__ wl,
    int* __restrict__ row_token, int* __restrict__ slot_of)
{
  __shared__ int pc[256][NE];
  __shared__ int base[NE], tot[NE];
  const int tid = threadIdx.x;
  int loc[NE] = {0,0,0,0,0,0,0,0};
  #pragma unroll 1
  for (int i = 0; i < 16; ++i) ++loc[topk[tid * 16 + i]];
  #pragma unroll
  for (int e = 0; e < NE; ++e) pc[tid][e] = loc[e];
  __syncthreads();
  if (tid < NE) {
    int acc = 0;
    for (int th = 0; th < 256; ++th) { int v = pc[th][tid]; pc[th][tid] = acc; acc += v; }
    tot[tid] = acc;
  }
  __syncthreads();
  if (tid == 0) {
    int acc = 0;
    for (int e = 0; e < NE; ++e) { base[e] = acc; acc += tot[e]; }
    int n = 0;
    for (int e = 0; e < NE; ++e)
      for (int r = 0; r < tot[e]; r += 256)
        wl[n++] = make_int4(e, base[e] + r, min(256, tot[e] - r), 0);
    for (int h = 0; h < 2; ++h)
      for (int mt = 0; mt < 8; ++mt)
        wl[n++] = make_int4(NE + h, mt * 256, 256, 0);
    for (int i = n; i < 64; ++i) wl[i] = make_int4(-1, 0, 0, 0);
  }
  __syncthreads();
  int pos[NE];
  #pragma unroll
  for (int e = 0; e < NE; ++e) pos[e] = base[e] + pc[tid][e];
  #pragma unroll 1
  for (int i = 0; i < 16; ++i) {
    const int gi = tid * 16 + i;
    const int e = topk[gi];
    const int s = pos[e]++;
    row_token[s] = gi >> 1;
    slot_of[gi] = s;
  }
}

// =====================================================================
// g13 NEW: per-wave 64x64 DUAL output.  512 thr / 8 waves (4M x 2N),
// BM=256, BN=128, BK=32, LDS 64KB (A 32 + B1 16 + B3 16).
// 2-barrier double-buffer, counted vmcnt(4), XOR swizzle, setprio.
// Per K-step/wave: 12 ds_read_b128, 32 MFMA (2x r12 FLOP/barrier).
// blockIdx.y in [0,40): GEMM tile wl[y]; [40,48): w2/sw2 conversion.
// =====================================================================
__global__ __launch_bounds__(512) void g13_kernel(
    const u16* __restrict__ xb, const int* __restrict__ row_token,
    const int4* __restrict__ wl,
    const u16* __restrict__ w1b, const float* __restrict__ b1,
    const u16* __restrict__ w3b, const float* __restrict__ b3,
    const u16* __restrict__ sw1b, const float* __restrict__ sb1,
    const u16* __restrict__ sw3b, const float* __restrict__ sb3,
    u16* __restrict__ Hr, u16* __restrict__ Hs,
    const float* __restrict__ w2f, const float* __restrict__ sw2f,
    u16* __restrict__ w2b, u16* __restrict__ sw2b)
{
  constexpr int K = DIM_;          // 1024
  constexpr int NT = K / 32;       // 32
  const int tid = threadIdx.x, wid = tid >> 6, lane = tid & 63;

  if (blockIdx.y >= 40) {          // ---- overlapped w2/sw2 conversion ----
    const int cid = (blockIdx.y - 40) * 11 + blockIdx.x;   // [0,88)
    for (int chunk = cid; chunk < 1760; chunk += 88) {
      int g = chunk; const float* src; u16* dst;
      if (g < 1408) { src = w2f;  dst = w2b;  }
      else { g -= 1408; src = sw2f; dst = sw2b; }
      const size_t base = (size_t)g * 8192 + (size_t)tid * 16;
      #pragma unroll
      for (int j = 0; j < 4; ++j) {
        float4 v = *(const float4*)(src + base + j * 4);
        *(u16x4*)(dst + base + j * 4) =
            (u16x4){ f2bf(v.x), f2bf(v.y), f2bf(v.z), f2bf(v.w) };
      }
    }
    return;
  }

  const int4 it = wl[blockIdx.y];
  const int z = it.x;
  if (z < 0) return;
  const int rowbase = it.y, rows_lim = it.z;
  const int col0 = blockIdx.x * 128;

  const int lrow = lane >> 2;
  const int sce = ((lane & 3) ^ ((lane >> 3) & 3)) * 8;   // swizzled src col

  const u16 *W1, *W3; const float *B1p, *B3p;
  u16* Hbase; int ldh;
  const u16* aptr[2];

  if (z < NE) {
    #pragma unroll
    for (int q = 0; q < 2; ++q) {
      const int rq = wid * 32 + q * 16 + lrow;
      const int t = (rq < rows_lim) ? row_token[rowbase + rq] : 0;
      aptr[q] = xb + (size_t)t * K + sce;
    }
    W1 = w1b + (size_t)z * INTER_ * K;  W3 = w3b + (size_t)z * INTER_ * K;
    B1p = b1 + z * INTER_;              B3p = b3 + z * INTER_;
    Hbase = Hr + (size_t)rowbase * INTER_;  ldh = INTER_;
  } else {
    const int h = z - NE;
    #pragma unroll
    for (int q = 0; q < 2; ++q) {
      const int rq = wid * 32 + q * 16 + lrow;
      aptr[q] = xb + (size_t)(rowbase + min(rq, rows_lim - 1)) * K + sce;
    }
    W1 = sw1b + (size_t)h * INTER_ * K;  W3 = sw3b + (size_t)h * INTER_ * K;
    B1p = sb1 + h * INTER_;              B3p = sb3 + h * INTER_;
    Hbase = Hs + (size_t)rowbase * SINT + h * INTER_;  ldh = SINT;
  }

  __shared__ alignas(16) u16 Al [2][256 * 32];   // 32 KB
  __shared__ alignas(16) u16 B1l[2][128 * 32];   // 16 KB
  __shared__ alignas(16) u16 B3l[2][128 * 32];   // 16 KB

  // B staging: each wave loads 16 rows of B1 AND 16 rows of B3
  const int brq = wid * 16 + lrow;                  // [0,128)
  const u16* b1src = W1 + (size_t)(col0 + brq) * K + sce;
  const u16* b3src = W3 + (size_t)(col0 + brq) * K + sce;

  #define G13_STAGE(p, kt) {                                          \
    const int k0_ = (kt) * 32;                                        \
    gload16(aptr[0] + k0_, &Al[p][(wid * 2 + 0) * 512]);              \
    gload16(aptr[1] + k0_, &Al[p][(wid * 2 + 1) * 512]);              \
    gload16(b1src + k0_, &B1l[p][wid * 512]);                         \
    gload16(b3src + k0_, &B3l[p][wid * 512]);                         \
  }

  G13_STAGE(0, 0);   // prologue: 4 loads/wave in flight

  const int wr = wid >> 1, wc = wid & 1, fr = lane & 15, gr = lane >> 4;
  const int key = (fr >> 1) & 3;
  f32x4 acc1[4][4] = {}, acc3[4][4] = {};
  int p = 0;

  #pragma unroll 1
  for (int kt = 0; kt < NT; ++kt) {
    if (kt + 1 < NT) { G13_STAGE(p ^ 1, kt + 1); WAITV(4); }
    else             { WAITV(0); }
    __builtin_amdgcn_s_barrier();
    u16x8 af[4], b1f[4], b3f[4];
    #pragma unroll
    for (int mi = 0; mi < 4; ++mi)
      af[mi] = *(const u16x8*)&Al[p][(wr * 64 + mi * 16 + fr) * 32 + ((gr ^ key) * 8)];
    #pragma unroll
    for (int ni = 0; ni < 4; ++ni) {
      const int off = (wc * 64 + ni * 16 + fr) * 32 + ((gr ^ key) * 8);
      b1f[ni] = *(const u16x8*)&B1l[p][off];
      b3f[ni] = *(const u16x8*)&B3l[p][off];
    }
    __builtin_amdgcn_s_setprio(1);
    #pragma unroll
    for (int mi = 0; mi < 4; ++mi)
      #pragma unroll
      for (int ni = 0; ni < 4; ++ni) {
        acc1[mi][ni] = mfma16(af[mi], b1f[ni], acc1[mi][ni]);
        acc3[mi][ni] = mfma16(af[mi], b3f[ni], acc3[mi][ni]);
      }
    __builtin_amdgcn_s_setprio(0);
    __builtin_amdgcn_s_barrier();
    p ^= 1;
  }
  #undef G13_STAGE

  #pragma unroll
  for (int ni = 0; ni < 4; ++ni) {
    const int gcol = col0 + wc * 64 + ni * 16 + fr;
    const float bb1 = B1p[gcol], bb3 = B3p[gcol];
    #pragma unroll
    for (int mi = 0; mi < 4; ++mi) {
      const int rb = wr * 64 + mi * 16 + gr * 4;
      #pragma unroll
      for (int j = 0; j < 4; ++j) {
        const int r = rb + j;
        if (r < rows_lim) {
          const float h1 = acc1[mi][ni][j] + bb1;
          const float h3 = acc3[mi][ni][j] + bb3;
          const float hv = (h1 / (1.0f + __expf(-h1))) * h3;
          Hbase[(size_t)r * ldh + gcol] = f2bf(hv);
        }
      }
    }
  }
}

// =====================================================================
// g2 (r12, unchanged): 512 thr / 8 waves (4M x 2N), BM=256, BN=128,
// BK=32, K=1408.  Triple-buffered, depth-2 prefetch, one barrier/step.
// z<8: A=Hr slots, W=w2b[z], out=Ys bf16 (+b2).
// z=8,9: A=Hs[:, h*1408:], W=sw2b[:, h*1408:], out=Zp[h] f32 (no bias).
// =====================================================================
__global__ __launch_bounds__(512) void g2_kernel(
    const u16* __restrict__ Hr, const u16* __restrict__ Hs,
    const int4* __restrict__ wl,
    const u16* __restrict__ w2b, const float* __restrict__ b2,
    const u16* __restrict__ sw2b,
    u16* __restrict__ Ys, float* __restrict__ Zp)
{
  constexpr int NT = INTER_ / 32;   // 44
  const int4 it = wl[blockIdx.y];
  const int z = it.x;
  if (z < 0) return;
  const int rowbase = it.y, rows_lim = it.z;
  const int col0 = blockIdx.x * 128;

  const int tid = threadIdx.x, wid = tid >> 6, lane = tid & 63;
  const int lrow = lane >> 2;
  const int sce = ((lane & 3) ^ ((lane >> 3) & 3)) * 8;

  const u16 *Abase, *W; const float* BB;
  int ldA, ldW;
  u16* Yout = nullptr; float* Zout = nullptr;
  if (z < NE) {
    Abase = Hr + (size_t)rowbase * INTER_;  ldA = INTER_;
    W = w2b + (size_t)z * DIM_ * INTER_;    ldW = INTER_;
    BB = b2 + z * DIM_;
    Yout = Ys + (size_t)rowbase * DIM_;
  } else {
    const int h = z - NE;
    Abase = Hs + (size_t)rowbase * SINT + h * INTER_;  ldA = SINT;
    W = sw2b + h * INTER_;                             ldW = SINT;
    BB = nullptr;
    Zout = Zp + (size_t)h * TOK * DIM_ + (size_t)rowbase * DIM_;
  }

  const u16* aptr[2];
  #pragma unroll
  for (int q = 0; q < 2; ++q) {
    const int rq = wid * 32 + q * 16 + lrow;
    aptr[q] = Abase + (size_t)min(rq, rows_lim - 1) * ldA + sce;
  }
  const u16* wsrc = W + (size_t)(col0 + wid * 16 + lrow) * ldW + sce;

  __shared__ alignas(16) u16 Al[3][256 * 32];   // 48 KB
  __shared__ alignas(16) u16 Bl[3][128 * 32];   // 24 KB

  #define G2_STAGE(p, kt) {                                           \
    const int k0_ = (kt) * 32;                                        \
    gload16(aptr[0] + k0_, &Al[p][(wid * 2 + 0) * 512]);              \
    gload16(aptr[1] + k0_, &Al[p][(wid * 2 + 1) * 512]);              \
    gload16(wsrc + k0_, &Bl[p][wid * 512]);                           \
  }

  G2_STAGE(0, 0);
  G2_STAGE(1, 1);   // 6 loads/wave in flight (2 stages)

  const int wr = wid >> 1, wc = wid & 1, fr = lane & 15, gr = lane >> 4;
  const int key = (fr >> 1) & 3;
  f32x4 acc[4][4] = {};
  int cur = 0;

  #pragma unroll 1
  for (int kt = 0; kt < NT; ++kt) {
    if (kt + 1 < NT) { WAITV(3); }
    else             { WAITV(0); }
    __builtin_amdgcn_s_barrier();
    if (kt + 2 < NT) {
      const int nx = (cur + 2 >= 3) ? cur - 1 : cur + 2;
      G2_STAGE(nx, kt + 2);
    }
    u16x8 af[4], bf_[4];
    #pragma unroll
    for (int mi = 0; mi < 4; ++mi)
      af[mi] = *(const u16x8*)&Al[cur][(wr * 64 + mi * 16 + fr) * 32 + ((gr ^ key) * 8)];
    #pragma unroll
    for (int ni = 0; ni < 4; ++ni)
      bf_[ni] = *(const u16x8*)&Bl[cur][(wc * 64 + ni * 16 + fr) * 32 + ((gr ^ key) * 8)];
    __builtin_amdgcn_s_setprio(1);
    #pragma unroll
    for (int mi = 0; mi < 4; ++mi)
      #pragma unroll
      for (int ni = 0; ni < 4; ++ni)
        acc[mi][ni] = mfma16(af[mi], bf_[ni], acc[mi][ni]);
    __builtin_amdgcn_s_setprio(0);
    cur = (cur + 1 == 3) ? 0 : cur + 1;
  }
  #undef G2_STAGE

  #pragma unroll
  for (int ni = 0; ni < 4; ++ni) {
    const int gcol = col0 + wc * 64 + ni * 16 + fr;
    const float bb = BB ? BB[gcol] : 0.0f;
    #pragma unroll
    for (int mi = 0; mi < 4; ++mi) {
      const int rb = wr * 64 + mi * 16 + gr * 4;
      #pragma unroll
      for (int j = 0; j < 4; ++j) {
        const int r = rb + j;
        if (r < rows_lim) {
          const float val = acc[mi][ni][j] + bb;
          if (z < NE) Yout[(size_t)r * DIM_ + gcol] = f2bf(val);
          else        Zout[(size_t)r * DIM_ + gcol] = val;
        }
      }
    }
  }
}

// =====================================================================
// combine: y = (Ys[s0]+Ys[s1])*scale + Zp0 + Zp1 + sb2
// =====================================================================
__global__ __launch_bounds__(256) void combine_kernel(
    const u16* __restrict__ Ys, const float* __restrict__ Zp,
    const int* __restrict__ slot_of, const float* __restrict__ scalep,
    const float* __restrict__ sb2, float* __restrict__ y_out)
{
  const int t = blockIdx.x, c = threadIdx.x * 4;
  const int s0 = slot_of[t * 2], s1 = slot_of[t * 2 + 1];
  const float s = scalep[t];
  u16x4 a = *(const u16x4*)(Ys + (size_t)s0 * DIM_ + c);
  u16x4 b = *(const u16x4*)(Ys + (size_t)s1 * DIM_ + c);
  float4 z0 = *(const float4*)(Zp + (size_t)t * DIM_ + c);
  float4 z1 = *(const float4*)(Zp + (size_t)TOK * DIM_ + (size_t)t * DIM_ + c);
  float4 sb = *(const float4*)(sb2 + c);
  float4 o;
  o.x = (bf2f(a[0]) + bf2f(b[0])) * s + z0.x + z1.x + sb.x;
  o.y = (bf2f(a[1]) + bf2f(b[1])) * s + z0.y + z1.y + sb.y;
  o.z = (bf2f(a[2]) + bf2f(b[2])) * s + z0.z + z1.z + sb.z;
  o.w = (bf2f(a[3]) + bf2f(b[3])) * s + z0.w + z1.w + sb.w;
  *(float4*)(y_out + (size_t)t * DIM_ + c) = o;
}

// =====================================================================
extern "C" void kernel_launch(void* const* d_in, const int* in_sizes, int n_in,
                              void* d_out, int out_size, void* d_ws, size_t ws_size,
                              hipStream_t stream) {
  (void)in_sizes; (void)n_in; (void)out_size; (void)ws_size;
  const float* x   = (const float*)d_in[0];
  const float* gw  = (const float*)d_in[1];
  const float* gb  = (const float*)d_in[2];
  const float* w1  = (const float*)d_in[3];
  const float* b1  = (const float*)d_in[4];
  const float* w2  = (const float*)d_in[5];
  const float* b2  = (const float*)d_in[6];
  const float* w3  = (const float*)d_in[7];
  const float* b3  = (const float*)d_in[8];
  const float* sw1 = (const float*)d_in[9];
  const float* sb1 = (const float*)d_in[10];
  const float* sw2 = (const float*)d_in[11];
  const float* sb2 = (const float*)d_in[12];
  const float* sw3 = (const float*)d_in[13];
  const float* sb3 = (const float*)d_in[14];

  float* out       = (float*)d_out;
  float* probs_out = out;
  float* idx_out   = out + TOK * NE;
  float* y_out     = out + TOK * NE + TOK * 2;

  char* ws = (char*)d_ws;
  u16*   xb        = (u16*)  (ws + XB_OFF);
  u16*   Hr        = (u16*)  (ws + HR_OFF);
  u16*   Hs        = (u16*)  (ws + HS_OFF);
  u16*   Ysl       = (u16*)  (ws + YS_OFF);
  float* Zp        = (float*)(ws + ZP_OFF);
  u16*   w1b       = (u16*)  (ws + W1B_OFF);
  u16*   w3b       = (u16*)  (ws + W3B_OFF);
  u16*   w2b       = (u16*)  (ws + W2B_OFF);
  u16*   sw1b      = (u16*)  (ws + SW1B_OFF);
  u16*   sw3b      = (u16*)  (ws + SW3B_OFF);
  u16*   sw2b      = (u16*)  (ws + SW2B_OFF);
  int*   topk      = (int*)  (ws + TOPK_OFF);
  float* scalep    = (float*)(ws + SCALE_OFF);
  int*   slot_of   = (int*)  (ws + SLOT_OFF);
  int*   row_token = (int*)  (ws + ROWT_OFF);
  int4*  wl        = (int4*) (ws + WL_OFF);

  gate_conv_kernel<<<512 + 7040, 256, 0, stream>>>(
      x, gw, gb, w1, w3, sw1, sw3,
      xb, w1b, w3b, sw1b, sw3b,
      probs_out, idx_out, topk, scalep);
  plan_kernel<<<1, 256, 0, stream>>>(topk, wl, row_token, slot_of);
  g13_kernel<<<dim3(11, 48), 512, 0, stream>>>(
      xb, row_token, wl, w1b, b1, w3b, b3, sw1b, sb1, sw3b, sb3, Hr, Hs,
      w2, sw2, w2b, sw2b);
  g2_kernel<<<dim3(8, 40), 512, 0, stream>>>(
      Hr, Hs, wl, w2b, b2, sw2b, Ysl, Zp);
  combine_kernel<<<TOK, 256, 0, stream>>>(Ysl, Zp, slot_of, scalep, sb2, y_out);
}

// Round 15
// 194.533 us; speedup vs baseline: 1.2421x; 1.1004x over previous
//
#include <hip/hip_runtime.h>
#include <math.h>

// ---------------- problem constants ----------------
static constexpr int TOK    = 2048;
static constexpr int DIM_   = 1024;
static constexpr int NE     = 8;
static constexpr int INTER_ = 1408;
static constexpr int SINT   = 2816;
static constexpr int NSLOT  = TOK * 2;

// ---------------- ws layout (bytes) ----------------
static constexpr size_t XB_OFF   = 0;                                    // [2048][1024] bf16
static constexpr size_t HR_OFF   = XB_OFF   + (size_t)TOK * DIM_ * 2;    // [4096][1408] bf16
static constexpr size_t HS_OFF   = HR_OFF   + (size_t)NSLOT * INTER_ * 2;// [2048][2816] bf16
static constexpr size_t YS_OFF   = HS_OFF   + (size_t)TOK * SINT * 2;    // [4096][1024] bf16
static constexpr size_t ZP_OFF   = YS_OFF   + (size_t)NSLOT * DIM_ * 2;  // [2][2048][1024] f32
static constexpr size_t W2B_OFF  = ZP_OFF   + (size_t)2 * TOK * DIM_ * 4;
static constexpr size_t SW2B_OFF = W2B_OFF  + (size_t)NE * DIM_ * INTER_ * 2;
static constexpr size_t TOPK_OFF = SW2B_OFF + (size_t)DIM_ * SINT * 2;
static constexpr size_t SCALE_OFF= TOPK_OFF + (size_t)TOK * 2 * 4;
static constexpr size_t SLOT_OFF = SCALE_OFF+ (size_t)TOK * 4;
static constexpr size_t ROWT_OFF = SLOT_OFF + (size_t)TOK * 2 * 4;
static constexpr size_t WL_OFF   = ROWT_OFF + (size_t)NSLOT * 4 + 1024;  // int4[64]

// ---------------- types / helpers ----------------
typedef unsigned short u16;
typedef u16   u16x4  __attribute__((ext_vector_type(4)));
typedef u16   u16x8  __attribute__((ext_vector_type(8)));
typedef __bf16 bf16x8 __attribute__((ext_vector_type(8)));
typedef float f32x4  __attribute__((ext_vector_type(4)));

static __device__ __forceinline__ u16 f2bf(float f) {
  unsigned int u = __builtin_bit_cast(unsigned int, f);
  return (u16)((u + 0x7fffu + ((u >> 16) & 1u)) >> 16);   // RNE
}
static __device__ __forceinline__ float bf2f(u16 h) {
  unsigned int u = ((unsigned int)h) << 16;
  return __builtin_bit_cast(float, u);
}
// packed f32x2 -> bf16x2 (RNE); lo result = first arg (r8/r10 verified)
static __device__ __forceinline__ unsigned int cvtpk(float lo, float hi) {
  unsigned int r;
  asm("v_cvt_pk_bf16_f32 %0, %1, %2" : "=v"(r) : "v"(lo), "v"(hi));
  return r;
}
static __device__ __forceinline__ f32x4 mfma16(u16x8 a, u16x8 b, f32x4 c) {
  return __builtin_amdgcn_mfma_f32_16x16x32_bf16(
      __builtin_bit_cast(bf16x8, a), __builtin_bit_cast(bf16x8, b), c, 0, 0, 0);
}
static __device__ __forceinline__ void gload16(const void* g, void* l) {
  __builtin_amdgcn_global_load_lds(
      (const __attribute__((address_space(1))) unsigned int*)g,
      (__attribute__((address_space(3))) unsigned int*)l, 16, 0, 0);
}
// counted vmcnt: keep newer prefetch loads in flight across the barrier (T4)
#define WAITV(N) asm volatile("s_waitcnt vmcnt(" #N ")" ::: "memory")

// =====================================================================
// gate: x -> bf16 + f64 gate scores, softmax, top-2.  512 blocks only.
// =====================================================================
__global__ __launch_bounds__(256) void gate_kernel(
    const float* __restrict__ x, const float* __restrict__ gw,
    const float* __restrict__ gb, u16* __restrict__ xb,
    float* __restrict__ probs_out, float* __restrict__ idx_out,
    int* __restrict__ topk, float* __restrict__ scalep)
{
  const int tid = threadIdx.x;
  {
    const size_t base = (size_t)blockIdx.x * 4096 + (size_t)tid * 16;
    const float4* src = (const float4*)(x + base);
    u16* dst = xb + base;
    #pragma unroll
    for (int j = 0; j < 4; ++j) {
      float4 v = src[j];
      *(u16x4*)(dst + j * 4) = (u16x4){ f2bf(v.x), f2bf(v.y), f2bf(v.z), f2bf(v.w) };
    }
  }
  const int wid = tid >> 6, lane = tid & 63;
  const int t = blockIdx.x * 4 + wid;
  const float* xr = x + (size_t)t * DIM_;
  double part[NE] = {0,0,0,0,0,0,0,0};
  for (int it = 0; it < DIM_ / 64; ++it) {
    const int d = lane + it * 64;
    const double xv = (double)xr[d];
    #pragma unroll
    for (int e = 0; e < NE; ++e) part[e] += xv * (double)gw[e * DIM_ + d];
  }
  #pragma unroll
  for (int e = 0; e < NE; ++e) {
    #pragma unroll
    for (int off = 32; off; off >>= 1) part[e] += __shfl_xor(part[e], off);
    part[e] += (double)gb[e];
  }
  if (lane == 0) {
    double m = part[0];
    #pragma unroll
    for (int e = 1; e < NE; ++e) m = fmax(m, part[e]);
    double p[NE], sd = 0.0;
    #pragma unroll
    for (int e = 0; e < NE; ++e) { p[e] = exp(part[e] - m); sd += p[e]; }
    float pf[NE]; float sumf = 0.0f;
    #pragma unroll
    for (int e = 0; e < NE; ++e) { pf[e] = (float)(p[e] / sd); sumf += pf[e]; }
    int a0 = 0;
    #pragma unroll
    for (int e = 1; e < NE; ++e) if (part[e] > part[a0]) a0 = e;
    int a1 = (a0 == 0) ? 1 : 0;
    #pragma unroll
    for (int e = 0; e < NE; ++e) if (e != a0 && part[e] > part[a1]) a1 = e;
    #pragma unroll
    for (int e = 0; e < NE; ++e) probs_out[t * NE + e] = pf[e];
    idx_out[t * 2 + 0] = (float)a0;
    idx_out[t * 2 + 1] = (float)a1;
    topk[t * 2 + 0] = a0; topk[t * 2 + 1] = a1;
    scalep[t] = sumf;
  }
}

// =====================================================================
// plan (r12, unchanged): histogram + bases + stable scatter + worklist.
// =====================================================================
__global__ __launch_bounds__(256) void plan_kernel(
    const int* __restrict__ topk, int4* __restrict__ wl,
    int* __restrict__ row_token, int* __restrict__ slot_of)
{
  __shared__ int pc[256][NE];
  __shared__ int base[NE], tot[NE];
  const int tid = threadIdx.x;
  int loc[NE] = {0,0,0,0,0,0,0,0};
  #pragma unroll 1
  for (int i = 0; i < 16; ++i) ++loc[topk[tid * 16 + i]];
  #pragma unroll
  for (int e = 0; e < NE; ++e) pc[tid][e] = loc[e];
  __syncthreads();
  if (tid < NE) {
    int acc = 0;
    for (int th = 0; th < 256; ++th) { int v = pc[th][tid]; pc[th][tid] = acc; acc += v; }
    tot[tid] = acc;
  }
  __syncthreads();
  if (tid == 0) {
    int acc = 0;
    for (int e = 0; e < NE; ++e) { base[e] = acc; acc += tot[e]; }
    int n = 0;
    for (int e = 0; e < NE; ++e)
      for (int r = 0; r < tot[e]; r += 256)
        wl[n++] = make_int4(e, base[e] + r, min(256, tot[e] - r), 0);
    for (int h = 0; h < 2; ++h)
      for (int mt = 0; mt < 8; ++mt)
        wl[n++] = make_int4(NE + h, mt * 256, 256, 0);
    for (int i = n; i < 64; ++i) wl[i] = make_int4(-1, 0, 0, 0);
  }
  __syncthreads();
  int pos[NE];
  #pragma unroll
  for (int e = 0; e < NE; ++e) pos[e] = base[e] + pc[tid][e];
  #pragma unroll 1
  for (int i = 0; i < 16; ++i) {
    const int gi = tid * 16 + i;
    const int e = topk[gi];
    const int s = pos[e]++;
    row_token[s] = gi >> 1;
    slot_of[gi] = s;
  }
}

// =====================================================================
// g13: r12 geometry (BM=256, BN=64 dual, BK=32, 8 waves, 2-barrier
// counted-vmcnt, XOR swizzle, setprio) but B = RAW F32 weights:
// gload_lds f32 tiles (16KB/buf/matrix), ds_read 2xb128 + cvt_pk.
// No weight pre-conversion for w1/w3/sw1/sw3.  LDS 64 KB.
// blockIdx.y in [0,40): GEMM tile wl[y]; [40,48): w2/sw2 conversion.
// =====================================================================
__global__ __launch_bounds__(512) void g13_kernel(
    const u16* __restrict__ xb, const int* __restrict__ row_token,
    const int4* __restrict__ wl,
    const float* __restrict__ w1, const float* __restrict__ b1,
    const float* __restrict__ w3, const float* __restrict__ b3,
    const float* __restrict__ sw1, const float* __restrict__ sb1,
    const float* __restrict__ sw3, const float* __restrict__ sb3,
    u16* __restrict__ Hr, u16* __restrict__ Hs,
    const float* __restrict__ w2f, const float* __restrict__ sw2f,
    u16* __restrict__ w2b, u16* __restrict__ sw2b)
{
  constexpr int K = DIM_;          // 1024
  constexpr int NT = K / 32;       // 32
  const int tid = threadIdx.x, wid = tid >> 6, lane = tid & 63;

  if (blockIdx.y >= 40) {          // ---- overlapped w2/sw2 conversion ----
    const int cid = (blockIdx.y - 40) * 22 + blockIdx.x;   // [0,176)
    for (int chunk = cid; chunk < 1760; chunk += 176) {
      int g = chunk; const float* src; u16* dst;
      if (g < 1408) { src = w2f;  dst = w2b;  }
      else { g -= 1408; src = sw2f; dst = sw2b; }
      const size_t base = (size_t)g * 8192 + (size_t)tid * 16;
      #pragma unroll
      for (int j = 0; j < 4; ++j) {
        float4 v = *(const float4*)(src + base + j * 4);
        *(u16x4*)(dst + base + j * 4) =
            (u16x4){ f2bf(v.x), f2bf(v.y), f2bf(v.z), f2bf(v.w) };
      }
    }
    return;
  }

  const int4 it = wl[blockIdx.y];
  const int z = it.x;
  if (z < 0) return;
  const int rowbase = it.y, rows_lim = it.z;
  const int col0 = blockIdx.x * 64;

  const int lrow = lane >> 2;
  const int sce = ((lane & 3) ^ ((lane >> 3) & 3)) * 8;   // A swizzled src col

  const float *W1, *W3, *B1p, *B3p;
  u16* Hbase; int ldh;
  const u16* aptr[2];

  if (z < NE) {
    #pragma unroll
    for (int q = 0; q < 2; ++q) {
      const int rq = wid * 32 + q * 16 + lrow;
      const int t = (rq < rows_lim) ? row_token[rowbase + rq] : 0;
      aptr[q] = xb + (size_t)t * K + sce;
    }
    W1 = w1 + (size_t)z * INTER_ * K;  W3 = w3 + (size_t)z * INTER_ * K;
    B1p = b1 + z * INTER_;             B3p = b3 + z * INTER_;
    Hbase = Hr + (size_t)rowbase * INTER_;  ldh = INTER_;
  } else {
    const int h = z - NE;
    #pragma unroll
    for (int q = 0; q < 2; ++q) {
      const int rq = wid * 32 + q * 16 + lrow;
      aptr[q] = xb + (size_t)(rowbase + min(rq, rows_lim - 1)) * K + sce;
    }
    W1 = sw1 + (size_t)h * INTER_ * K;  W3 = sw3 + (size_t)h * INTER_ * K;
    B1p = sb1 + h * INTER_;             B3p = sb3 + h * INTER_;
    Hbase = Hs + (size_t)rowbase * SINT + h * INTER_;  ldh = SINT;
  }

  __shared__ alignas(16) u16   Al [2][256 * 32];   // 32 KB (bf16 A)
  __shared__ alignas(16) float B1f[2][64 * 32];    // 16 KB (f32 B1)
  __shared__ alignas(16) float B3f[2][64 * 32];    // 16 KB (f32 B3)

  // B staging roles (f32): waves 0-3 -> B1, waves 4-7 -> B3; 16 rows/wave,
  // 2 gload16 per wave (l=0,1).  idx = lane + l*64 in [0,128):
  // row16 = idx>>3, chunk = idx&7, swizzle key = row16&7 (pre-swz source).
  const int brole = wid >> 2, bw = wid & 3;
  const float* Wb = brole ? W3 : W1;
  const float* bsrcf[2];
  #pragma unroll
  for (int l = 0; l < 2; ++l) {
    const int idx = lane + l * 64;
    bsrcf[l] = Wb + (size_t)(col0 + bw * 16 + (idx >> 3)) * K
                  + (((idx & 7) ^ ((idx >> 3) & 7)) * 4);
  }

  #define G13_STAGE(p, kt) {                                            \
    const int k0_ = (kt) * 32;                                          \
    gload16(aptr[0] + k0_, &Al[p][(wid * 2 + 0) * 512]);                \
    gload16(aptr[1] + k0_, &Al[p][(wid * 2 + 1) * 512]);                \
    float* bb_ = brole ? &B3f[p][bw * 512] : &B1f[p][bw * 512];         \
    gload16(bsrcf[0] + k0_, bb_ + lane * 4);                            \
    gload16(bsrcf[1] + k0_, bb_ + (lane + 64) * 4);                     \
  }

  G13_STAGE(0, 0);   // prologue: 4 loads/wave in flight

  const int wr = wid >> 1, wc = wid & 1, fr = lane & 15, gr = lane >> 4;
  const int key = (fr >> 1) & 3;       // A read key (4-chunk rows)
  const int keyb = fr & 7;             // B read key (8-chunk f32 rows)
  f32x4 acc1[4][2] = {}, acc3[4][2] = {};
  int p = 0;

  #pragma unroll 1
  for (int kt = 0; kt < NT; ++kt) {
    if (kt + 1 < NT) { G13_STAGE(p ^ 1, kt + 1); WAITV(4); }
    else             { WAITV(0); }
    __builtin_amdgcn_s_barrier();
    u16x8 af[4], b1f[2], b3f[2];
    #pragma unroll
    for (int mi = 0; mi < 4; ++mi)
      af[mi] = *(const u16x8*)&Al[p][(wr * 64 + mi * 16 + fr) * 32 + ((gr ^ key) * 8)];
    #pragma unroll
    for (int ni = 0; ni < 2; ++ni) {
      const int rb = wc * 32 + ni * 16 + fr;            // B row (output col)
      const int c0 = (2 * gr) ^ keyb;                   // low 4 f32
      const int c1 = c0 ^ 1;                            // high 4 f32
      const float* p1 = &B1f[p][rb * 32];
      const float* p3 = &B3f[p][rb * 32];
      f32x4 lo1 = *(const f32x4*)(p1 + c0 * 4);
      f32x4 hi1 = *(const f32x4*)(p1 + c1 * 4);
      f32x4 lo3 = *(const f32x4*)(p3 + c0 * 4);
      f32x4 hi3 = *(const f32x4*)(p3 + c1 * 4);
      uint4 t1, t3;
      t1.x = cvtpk(lo1[0], lo1[1]); t1.y = cvtpk(lo1[2], lo1[3]);
      t1.z = cvtpk(hi1[0], hi1[1]); t1.w = cvtpk(hi1[2], hi1[3]);
      t3.x = cvtpk(lo3[0], lo3[1]); t3.y = cvtpk(lo3[2], lo3[3]);
      t3.z = cvtpk(hi3[0], hi3[1]); t3.w = cvtpk(hi3[2], hi3[3]);
      b1f[ni] = __builtin_bit_cast(u16x8, t1);
      b3f[ni] = __builtin_bit_cast(u16x8, t3);
    }
    __builtin_amdgcn_s_setprio(1);
    #pragma unroll
    for (int mi = 0; mi < 4; ++mi)
      #pragma unroll
      for (int ni = 0; ni < 2; ++ni) {
        acc1[mi][ni] = mfma16(af[mi], b1f[ni], acc1[mi][ni]);
        acc3[mi][ni] = mfma16(af[mi], b3f[ni], acc3[mi][ni]);
      }
    __builtin_amdgcn_s_setprio(0);
    __builtin_amdgcn_s_barrier();
    p ^= 1;
  }
  #undef G13_STAGE

  #pragma unroll
  for (int ni = 0; ni < 2; ++ni) {
    const int gcol = col0 + wc * 32 + ni * 16 + fr;
    const float bb1 = B1p[gcol], bb3 = B3p[gcol];
    #pragma unroll
    for (int mi = 0; mi < 4; ++mi) {
      const int rb = wr * 64 + mi * 16 + gr * 4;
      #pragma unroll
      for (int j = 0; j < 4; ++j) {
        const int r = rb + j;
        if (r < rows_lim) {
          const float h1 = acc1[mi][ni][j] + bb1;
          const float h3 = acc3[mi][ni][j] + bb3;
          const float hv = (h1 / (1.0f + __expf(-h1))) * h3;
          Hbase[(size_t)r * ldh + gcol] = f2bf(hv);
        }
      }
    }
  }
}

// =====================================================================
// g2 (r12, unchanged): 512 thr / 8 waves (4M x 2N), BM=256, BN=128,
// BK=32, K=1408.  Triple-buffered, depth-2 prefetch, one barrier/step.
// z<8: A=Hr slots, W=w2b[z], out=Ys bf16 (+b2).
// z=8,9: A=Hs[:, h*1408:], W=sw2b[:, h*1408:], out=Zp[h] f32 (no bias).
// =====================================================================
__global__ __launch_bounds__(512) void g2_kernel(
    const u16* __restrict__ Hr, const u16* __restrict__ Hs,
    const int4* __restrict__ wl,
    const u16* __restrict__ w2b, const float* __restrict__ b2,
    const u16* __restrict__ sw2b,
    u16* __restrict__ Ys, float* __restrict__ Zp)
{
  constexpr int NT = INTER_ / 32;   // 44
  const int4 it = wl[blockIdx.y];
  const int z = it.x;
  if (z < 0) return;
  const int rowbase = it.y, rows_lim = it.z;
  const int col0 = blockIdx.x * 128;

  const int tid = threadIdx.x, wid = tid >> 6, lane = tid & 63;
  const int lrow = lane >> 2;
  const int sce = ((lane & 3) ^ ((lane >> 3) & 3)) * 8;

  const u16 *Abase, *W; const float* BB;
  int ldA, ldW;
  u16* Yout = nullptr; float* Zout = nullptr;
  if (z < NE) {
    Abase = Hr + (size_t)rowbase * INTER_;  ldA = INTER_;
    W = w2b + (size_t)z * DIM_ * INTER_;    ldW = INTER_;
    BB = b2 + z * DIM_;
    Yout = Ys + (size_t)rowbase * DIM_;
  } else {
    const int h = z - NE;
    Abase = Hs + (size_t)rowbase * SINT + h * INTER_;  ldA = SINT;
    W = sw2b + h * INTER_;                             ldW = SINT;
    BB = nullptr;
    Zout = Zp + (size_t)h * TOK * DIM_ + (size_t)rowbase * DIM_;
  }

  const u16* aptr[2];
  #pragma unroll
  for (int q = 0; q < 2; ++q) {
    const int rq = wid * 32 + q * 16 + lrow;
    aptr[q] = Abase + (size_t)min(rq, rows_lim - 1) * ldA + sce;
  }
  const u16* wsrc = W + (size_t)(col0 + wid * 16 + lrow) * ldW + sce;

  __shared__ alignas(16) u16 Al[3][256 * 32];   // 48 KB
  __shared__ alignas(16) u16 Bl[3][128 * 32];   // 24 KB

  #define G2_STAGE(p, kt) {                                           \
    const int k0_ = (kt) * 32;                                        \
    gload16(aptr[0] + k0_, &Al[p][(wid * 2 + 0) * 512]);              \
    gload16(aptr[1] + k0_, &Al[p][(wid * 2 + 1) * 512]);              \
    gload16(wsrc + k0_, &Bl[p][wid * 512]);                           \
  }

  G2_STAGE(0, 0);
  G2_STAGE(1, 1);   // 6 loads/wave in flight (2 stages)

  const int wr = wid >> 1, wc = wid & 1, fr = lane & 15, gr = lane >> 4;
  const int key = (fr >> 1) & 3;
  f32x4 acc[4][4] = {};
  int cur = 0;

  #pragma unroll 1
  for (int kt = 0; kt < NT; ++kt) {
    if (kt + 1 < NT) { WAITV(3); }
    else             { WAITV(0); }
    __builtin_amdgcn_s_barrier();
    if (kt + 2 < NT) {
      const int nx = (cur + 2 >= 3) ? cur - 1 : cur + 2;
      G2_STAGE(nx, kt + 2);
    }
    u16x8 af[4], bf_[4];
    #pragma unroll
    for (int mi = 0; mi < 4; ++mi)
      af[mi] = *(const u16x8*)&Al[cur][(wr * 64 + mi * 16 + fr) * 32 + ((gr ^ key) * 8)];
    #pragma unroll
    for (int ni = 0; ni < 4; ++ni)
      bf_[ni] = *(const u16x8*)&Bl[cur][(wc * 64 + ni * 16 + fr) * 32 + ((gr ^ key) * 8)];
    __builtin_amdgcn_s_setprio(1);
    #pragma unroll
    for (int mi = 0; mi < 4; ++mi)
      #pragma unroll
      for (int ni = 0; ni < 4; ++ni)
        acc[mi][ni] = mfma16(af[mi], bf_[ni], acc[mi][ni]);
    __builtin_amdgcn_s_setprio(0);
    cur = (cur + 1 == 3) ? 0 : cur + 1;
  }
  #undef G2_STAGE

  #pragma unroll
  for (int ni = 0; ni < 4; ++ni) {
    const int gcol = col0 + wc * 64 + ni * 16 + fr;
    const float bb = BB ? BB[gcol] : 0.0f;
    #pragma unroll
    for (int mi = 0; mi < 4; ++mi) {
      const int rb = wr * 64 + mi * 16 + gr * 4;
      #pragma unroll
      for (int j = 0; j < 4; ++j) {
        const int r = rb + j;
        if (r < rows_lim) {
          const float val = acc[mi][ni][j] + bb;
          if (z < NE) Yout[(size_t)r * DIM_ + gcol] = f2bf(val);
          else        Zout[(size_t)r * DIM_ + gcol] = val;
        }
      }
    }
  }
}

// =====================================================================
// combine: y = (Ys[s0]+Ys[s1])*scale + Zp0 + Zp1 + sb2
// =====================================================================
__global__ __launch_bounds__(256) void combine_kernel(
    const u16* __restrict__ Ys, const float* __restrict__ Zp,
    const int* __restrict__ slot_of, const float* __restrict__ scalep,
    const float* __restrict__ sb2, float* __restrict__ y_out)
{
  const int t = blockIdx.x, c = threadIdx.x * 4;
  const int s0 = slot_of[t * 2], s1 = slot_of[t * 2 + 1];
  const float s = scalep[t];
  u16x4 a = *(const u16x4*)(Ys + (size_t)s0 * DIM_ + c);
  u16x4 b = *(const u16x4*)(Ys + (size_t)s1 * DIM_ + c);
  float4 z0 = *(const float4*)(Zp + (size_t)t * DIM_ + c);
  float4 z1 = *(const float4*)(Zp + (size_t)TOK * DIM_ + (size_t)t * DIM_ + c);
  float4 sb = *(const float4*)(sb2 + c);
  float4 o;
  o.x = (bf2f(a[0]) + bf2f(b[0])) * s + z0.x + z1.x + sb.x;
  o.y = (bf2f(a[1]) + bf2f(b[1])) * s + z0.y + z1.y + sb.y;
  o.z = (bf2f(a[2]) + bf2f(b[2])) * s + z0.z + z1.z + sb.z;
  o.w = (bf2f(a[3]) + bf2f(b[3])) * s + z0.w + z1.w + sb.w;
  *(float4*)(y_out + (size_t)t * DIM_ + c) = o;
}

// =====================================================================
extern "C" void kernel_launch(void* const* d_in, const int* in_sizes, int n_in,
                              void* d_out, int out_size, void* d_ws, size_t ws_size,
                              hipStream_t stream) {
  (void)in_sizes; (void)n_in; (void)out_size; (void)ws_size;
  const float* x   = (const float*)d_in[0];
  const float* gw  = (const float*)d_in[1];
  const float* gb  = (const float*)d_in[2];
  const float* w1  = (const float*)d_in[3];
  const float* b1  = (const float*)d_in[4];
  const float* w2  = (const float*)d_in[5];
  const float* b2  = (const float*)d_in[6];
  const float* w3  = (const float*)d_in[7];
  const float* b3  = (const float*)d_in[8];
  const float* sw1 = (const float*)d_in[9];
  const float* sb1 = (const float*)d_in[10];
  const float* sw2 = (const float*)d_in[11];
  const float* sb2 = (const float*)d_in[12];
  const float* sw3 = (const float*)d_in[13];
  const float* sb3 = (const float*)d_in[14];

  float* out       = (float*)d_out;
  float* probs_out = out;
  float* idx_out   = out + TOK * NE;
  float* y_out     = out + TOK * NE + TOK * 2;

  char* ws = (char*)d_ws;
  u16*   xb        = (u16*)  (ws + XB_OFF);
  u16*   Hr        = (u16*)  (ws + HR_OFF);
  u16*   Hs        = (u16*)  (ws + HS_OFF);
  u16*   Ysl       = (u16*)  (ws + YS_OFF);
  float* Zp        = (float*)(ws + ZP_OFF);
  u16*   w2b       = (u16*)  (ws + W2B_OFF);
  u16*   sw2b      = (u16*)  (ws + SW2B_OFF);
  int*   topk      = (int*)  (ws + TOPK_OFF);
  float* scalep    = (float*)(ws + SCALE_OFF);
  int*   slot_of   = (int*)  (ws + SLOT_OFF);
  int*   row_token = (int*)  (ws + ROWT_OFF);
  int4*  wl        = (int4*) (ws + WL_OFF);

  gate_kernel<<<512, 256, 0, stream>>>(x, gw, gb, xb, probs_out, idx_out,
                                       topk, scalep);
  plan_kernel<<<1, 256, 0, stream>>>(topk, wl, row_token, slot_of);
  g13_kernel<<<dim3(22, 48), 512, 0, stream>>>(
      xb, row_token, wl, w1, b1, w3, b3, sw1, sb1, sw3, sb3, Hr, Hs,
      w2, sw2, w2b, sw2b);
  g2_kernel<<<dim3(8, 40), 512, 0, stream>>>(
      Hr, Hs, wl, w2b, b2, sw2b, Ysl, Zp);
  combine_kernel<<<TOK, 256, 0, stream>>>(Ysl, Zp, slot_of, scalep, sb2, y_out);
}